// Round 1
// baseline (978.064 us; speedup 1.0000x reference)
//
#include <hip/hip_runtime.h>

// MSDNet on gfx950 — round 13: fuse all 30 depth kernels into ONE persistent
// cooperative kernel. R12 analysis: each depth kernel is ~3-5 us of work but
// costs ~16 us wall (dispatch ramp + tail drain + inter-kernel gap + boundary
// cache flush x30). New structure: 256 blocks x 512 threads (same 2048 row-
// waves, same XCD band swizzle, now 8 consecutive rows/CU), hand-rolled
// agent-scope grid barrier between depths (release atomic + wbl2, relaxed
// s_sleep spin, single acquire+inv on exit). Depth bodies are the validated
// R12 code, untouched, shared between the fused kernel and a full legacy
// fallback path used iff hipLaunchCooperativeKernel returns an error.

#define MSD_DEPTH 30
#define NB 4
#define IH 512
#define IW 512
#define HALO 16
#define WPp (IW + 2 * HALO)               /* 544 u32 per row */
#define HPp (IH + 2 * HALO)               /* 544 rows */
#define PLANE_U ((size_t)WPp * HPp)       /* u32 per subplane */
#define PSTR ((size_t)NB * PLANE_U)       /* pair stride (u32) */
#define NPAIR 15
#define NPIX (NB * IH * IW)
#define WPK_OFF ((size_t)20 << 20)        /* u32 offset: 80 MB into ws */
#define NBLK 256                          /* fused grid: 1 block/CU */
#define TPB 512                           /* 8 waves/block */
#define ZSTRIPS (32 * (WPp / 4) * NPAIR * NB) /* 261120 */

typedef _Float16 h2v __attribute__((ext_vector_type(2)));
typedef unsigned int u32;

__device__ __forceinline__ float fdot2u(u32 a, u32 b, float c) {
#if __has_builtin(__builtin_amdgcn_fdot2)
    return __builtin_amdgcn_fdot2(__builtin_bit_cast(h2v, a),
                                  __builtin_bit_cast(h2v, b), c, false);
#else
    h2v x = __builtin_bit_cast(h2v, a), y = __builtin_bit_cast(h2v, b);
    return c + (float)x[0] * (float)y[0] + (float)x[1] * (float)y[1];
#endif
}

// ---------------------------------------------------------------------------
// Shared phase bodies (used by both the fused kernel and the legacy path).
// ---------------------------------------------------------------------------
__device__ __forceinline__ void pack_weights_body(int idx,
                                                  const float* __restrict__ Wmsd,
                                                  const float* __restrict__ convW,
                                                  u32* __restrict__ wpk,
                                                  u32* __restrict__ cpk) {
    if (idx < MSD_DEPTH * NPAIR * 9) {
        int I = idx / (NPAIR * 9);
        int rem = idx - I * (NPAIR * 9);
        int p = rem / 9, t = rem - p * 9;
        int NC = I + 1, c0 = 2 * p, c1 = 2 * p + 1;
        h2v pk;
        pk[0] = (_Float16)((c0 < NC) ? Wmsd[((size_t)I * MSD_DEPTH + c0) * 9 + t] : 0.f);
        pk[1] = (_Float16)((c1 < NC) ? Wmsd[((size_t)I * MSD_DEPTH + c1) * 9 + t] : 0.f);
        wpk[idx] = __builtin_bit_cast(u32, pk);
    }
    if (idx < NPAIR) {
        h2v pk;
        pk[0] = (_Float16)convW[2 * idx];
        pk[1] = (_Float16)convW[2 * idx + 1];
        cpk[idx] = __builtin_bit_cast(u32, pk);
    }
}

__device__ __forceinline__ void zero_halo_body(int idx, u32* __restrict__ feats) {
    const int per = 32 * (WPp / 4); // 32 rows x 136 uint4 strips = 4352
    int sub = idx / per;
    int s = idx - sub * per;
    int rr = s / 136;
    int c4 = (s - rr * 136) * 4;
    int r = (rr < 16) ? rr : (IH + HALO) + (rr - 16);
    uint4 z = {0, 0, 0, 0};
    *(uint4*)(feats + (size_t)sub * PLANE_U + (size_t)r * WPp + c4) = z;
}

__device__ __forceinline__ void scale_in_body(int s, const float* __restrict__ x,
                                              u32* __restrict__ feats,
                                              const float* __restrict__ sw,
                                              const float* __restrict__ sb) {
    int idx = s * 8;
    int b = idx >> 18;
    int y = (idx >> 9) & 511;
    int xx = idx & 511;
    const float sws = sw[0], sbs = sb[0];
    u32 v[8];
#pragma unroll
    for (int j = 0; j < 8; ++j) {
        _Float16 h = (_Float16)(x[idx + j] * sws + sbs);
        v[j] = (u32)__builtin_bit_cast(unsigned short, h);
    }
    u32* q = feats + (size_t)b * PLANE_U + (size_t)(y + HALO) * WPp + HALO + xx;
    *(uint4*)q = *(uint4*)&v[0];
    *(uint4*)(q + 4) = *(uint4*)&v[4];
}

// ---------------------------------------------------------------------------
// Depth body — identical arithmetic/layout to validated R12 depth_kernel<I>.
// ---------------------------------------------------------------------------
template <int I>
__device__ __forceinline__ void depth_body(int b, int y, int lane,
                                           u32* __restrict__ feats,
                                           const u32* __restrict__ wpk,
                                           const u32* __restrict__ cpk,
                                           const float* __restrict__ bias,
                                           const float* __restrict__ convW,
                                           const float* __restrict__ convB,
                                           const float* __restrict__ soutw,
                                           const float* __restrict__ soutb,
                                           float* __restrict__ out) {
    constexpr int D = (I % 10) + 1;
    constexpr int NC = I + 1;
    constexpr int NP = (NC + 1) / 2;
    constexpr bool LAST = (I == MSD_DEPTH - 1);

    // bpermute byte addresses for lane offsets -2,-1,+1,+2 (wrap is masked).
    const int bp_m2 = ((lane - 2) & 63) << 2;
    const int bp_m1 = ((lane - 1) & 63) << 2;
    const int bp_p1 = ((lane + 1) & 63) << 2;
    const int bp_p2 = ((lane + 2) & 63) << 2;

    u32* const pb = feats + (size_t)b * PLANE_U + (size_t)(y + HALO) * WPp + HALO + lane * 8;

    float acc[8], ydot[8];
#pragma unroll
    for (int j = 0; j < 8; ++j) { acc[j] = 0.f; ydot[j] = 0.f; }

    const u32* const wrb = wpk + (size_t)I * (NPAIR * 9);

    u32 A[3][8], B[3][8];

    auto load_pair = [&](u32 (*buf)[8], int p) {
        const u32* pp = pb + (size_t)p * PSTR;
#pragma unroll
        for (int r = 0; r < 3; ++r) {
            const u32* rp = pp + (ptrdiff_t)(r - 1) * (D * WPp);
            *(uint4*)&buf[r][0] = *(const uint4*)rp;
            *(uint4*)&buf[r][4] = *(const uint4*)(rp + 4);
        }
    };

    // w[k] = dword at row-pixel (lane*8 + k + shift), 0 outside [0,512).
    auto window = [&](const u32* d, int shift, u32* w) {
#pragma unroll
        for (int k = 0; k < 8; ++k) {
            int off = k + shift; // constant-folded (shift = +-D, k unrolled)
            if (off >= 0 && off < 8) {
                w[k] = d[off];
            } else {
                int q = off >> 3;            // floor div 8: -2,-1,1,2
                int idx = off - q * 8;       // 0..7
                int addr = (q == -2) ? bp_m2
                         : (q == -1) ? bp_m1
                         : (q == 1)  ? bp_p1 : bp_p2;
                u32 t = (u32)__builtin_amdgcn_ds_bpermute(addr, (int)d[idx]);
                bool valid = (q < 0) ? (lane >= -q) : (lane <= 63 - q);
                w[k] = valid ? t : 0u;
            }
        }
    };

    auto compute = [&](u32 (*buf)[8], int p) {
        const u32* wq = wrb + p * 9; // wave-uniform -> s_load
        const u32 cw = LAST ? cpk[p] : 0u;
#pragma unroll
        for (int r = 0; r < 3; ++r) {
            u32* d = buf[r];
            u32 wl[8], wrr[8];
            window(d, -D, wl);
            window(d, D, wrr);
            const u32 w0 = wq[r * 3 + 0], w1 = wq[r * 3 + 1], w2 = wq[r * 3 + 2];
#pragma unroll
            for (int k = 0; k < 8; ++k) {
                float a = acc[k];
                a = fdot2u(wl[k], w0, a);
                a = fdot2u(d[k], w1, a);
                a = fdot2u(wrr[k], w2, a);
                acc[k] = a;
            }
            if (LAST && r == 1) {
#pragma unroll
                for (int k = 0; k < 8; ++k) ydot[k] = fdot2u(d[k], cw, ydot[k]);
            }
        }
    };

    // 2-deep software pipeline over channel pairs (validated R8).
    load_pair(A, 0);
    int p = 0;
    for (; p + 2 <= NP; p += 2) {
        load_pair(B, p + 1);
        compute(A, p);
        if (p + 2 < NP) load_pair(A, p + 2);
        compute(B, p + 1);
    }
    if (p < NP) compute(A, p);

    const float b0 = bias[I];
    if (!LAST) {
        // Merge h (channel NC) into pair NC>>1. NC odd: hi16 (partner lo16 =
        // channel NC-1, reloaded L2-hot). NC even: lo16, hi16 = 0.
        u32 part[8];
        if constexpr ((NC & 1) != 0) {
            const u32* rp = pb + (size_t)(NP - 1) * PSTR;
            *(uint4*)&part[0] = *(const uint4*)rp;
            *(uint4*)&part[4] = *(const uint4*)(rp + 4);
        }
        u32 mg[8];
#pragma unroll
        for (int j = 0; j < 8; ++j) {
            float h = acc[j] + b0;
            h = h > 0.f ? h : 0.f;
            u32 h16 = (u32)__builtin_bit_cast(unsigned short, (_Float16)h);
            if constexpr ((NC & 1) != 0)
                mg[j] = (part[j] & 0xFFFFu) | (h16 << 16);
            else
                mg[j] = h16;
        }
        u32* q = feats + (size_t)(NC >> 1) * PSTR + (size_t)b * PLANE_U +
                 (size_t)(y + HALO) * WPp + HALO + lane * 8;
        *(uint4*)q = *(uint4*)&mg[0];
        *(uint4*)(q + 4) = *(uint4*)&mg[4];
    } else {
        const float cw30 = convW[MSD_DEPTH];
        const float cb = convB[0], ow = soutw[0], ob = soutb[0];
        float* q = out + ((size_t)b * IH + y) * IW + lane * 8;
        float o[8];
#pragma unroll
        for (int j = 0; j < 8; ++j) {
            float h = acc[j] + b0;
            h = h > 0.f ? h : 0.f;
            float yv = ydot[j] + cw30 * h + cb;
            o[j] = yv * ow + ob;
        }
        *(uint4*)q = *(uint4*)&o[0];
        *(uint4*)(q + 4) = *(uint4*)&o[4];
    }
}

// ---------------------------------------------------------------------------
// Legacy (fallback) kernels — exact R12 behavior.
// ---------------------------------------------------------------------------
__global__ __launch_bounds__(256) void pack_weights(const float* __restrict__ Wmsd,
                                                    const float* __restrict__ convW,
                                                    u32* __restrict__ wpk,
                                                    u32* __restrict__ cpk) {
    int idx = blockIdx.x * 256 + threadIdx.x;
    pack_weights_body(idx, Wmsd, convW, wpk, cpk);
}

__global__ __launch_bounds__(256) void zero_halo_kernel(u32* __restrict__ feats) {
    int idx = blockIdx.x * 256 + threadIdx.x;
    if (idx >= ZSTRIPS) return;
    zero_halo_body(idx, feats);
}

__global__ __launch_bounds__(256) void scale_in_kernel(const float* __restrict__ x,
                                                       u32* __restrict__ feats,
                                                       const float* __restrict__ sw,
                                                       const float* __restrict__ sb) {
    int s = blockIdx.x * 256 + threadIdx.x;
    scale_in_body(s, x, feats, sw, sb);
}

template <int I>
__global__ __launch_bounds__(128, 2) void depth_kernel(u32* __restrict__ feats,
                                                       const u32* __restrict__ wpk,
                                                       const u32* __restrict__ cpk,
                                                       const float* __restrict__ bias,
                                                       const float* __restrict__ convW,
                                                       const float* __restrict__ convB,
                                                       const float* __restrict__ soutw,
                                                       const float* __restrict__ soutb,
                                                       float* __restrict__ out) {
    const int tid = threadIdx.x;
    const int widx = tid >> 6, lane = tid & 63;
    const int bid = blockIdx.x; // 1024 blocks x 2 waves = rows
    const int xcd = bid & 7;
    const int kk = bid >> 3; // 0..127
    const int b = xcd >> 1;
    const int y = (xcd & 1) * 256 + kk * 2 + widx;
    depth_body<I>(b, y, lane, feats, wpk, cpk, bias, convW, convB, soutw, soutb, out);
}

// ---------------------------------------------------------------------------
// Fused persistent cooperative kernel.
// ---------------------------------------------------------------------------
__global__ void init_bar(u32* __restrict__ bar) {
    if (threadIdx.x == 0) *bar = 0u;
}

// Agent-scope grid barrier: release arrive (wbl2), relaxed spin w/ s_sleep
// backoff (no repeated L2 invalidation while others compute), one acquire
// (inv) on exit. Requires all NBLK blocks co-resident (cooperative launch).
__device__ __forceinline__ void gsync(u32* bar, u32 target) {
    __syncthreads();
    if (threadIdx.x == 0) {
        __hip_atomic_fetch_add(bar, 1u, __ATOMIC_RELEASE, __HIP_MEMORY_SCOPE_AGENT);
        while (__hip_atomic_load(bar, __ATOMIC_RELAXED, __HIP_MEMORY_SCOPE_AGENT) < target)
            __builtin_amdgcn_s_sleep(2);
        (void)__hip_atomic_load(bar, __ATOMIC_ACQUIRE, __HIP_MEMORY_SCOPE_AGENT);
    }
    __syncthreads();
}

__global__ __launch_bounds__(TPB, 2) void msd_fused(const float* __restrict__ x,
                                                    const float* __restrict__ Wmsd,
                                                    const float* __restrict__ bias,
                                                    const float* __restrict__ convW,
                                                    const float* __restrict__ convB,
                                                    const float* __restrict__ sinw,
                                                    const float* __restrict__ sinb,
                                                    const float* __restrict__ soutw,
                                                    const float* __restrict__ soutb,
                                                    u32* __restrict__ feats,
                                                    u32* __restrict__ wpk,
                                                    u32* __restrict__ cpk,
                                                    u32* __restrict__ bar,
                                                    float* __restrict__ out) {
    const int tid = threadIdx.x;
    const int gtid = blockIdx.x * TPB + tid; // 0..131071

    // ---- phase 0: pack weights + zero halos + scale input (disjoint) ----
    pack_weights_body(gtid, Wmsd, convW, wpk, cpk);
    for (int it = gtid; it < ZSTRIPS; it += NBLK * TPB) zero_halo_body(it, feats);
    scale_in_body(gtid, x, feats, sinw, sinb); // NPIX/8 == NBLK*TPB exactly

    // ---- row mapping: 256 blocks x 8 waves; 8 consecutive rows per CU ----
    const int lane = tid & 63;
    const int widx = tid >> 6;               // 0..7
    const int bid = blockIdx.x;
    const int xcd = bid & 7;                 // XCD band swizzle (validated R4-R8)
    const int b = xcd >> 1;
    const int y = (xcd & 1) * 256 + (bid >> 3) * 8 + widx;

    u32 tgt = NBLK;
    gsync(bar, tgt);

#define RUNSYNC(I)                                                                 \
    depth_body<I>(b, y, lane, feats, wpk, cpk, bias, convW, convB, soutw, soutb,   \
                  out);                                                            \
    tgt += NBLK;                                                                   \
    gsync(bar, tgt);

    RUNSYNC(0)  RUNSYNC(1)  RUNSYNC(2)  RUNSYNC(3)  RUNSYNC(4)
    RUNSYNC(5)  RUNSYNC(6)  RUNSYNC(7)  RUNSYNC(8)  RUNSYNC(9)
    RUNSYNC(10) RUNSYNC(11) RUNSYNC(12) RUNSYNC(13) RUNSYNC(14)
    RUNSYNC(15) RUNSYNC(16) RUNSYNC(17) RUNSYNC(18) RUNSYNC(19)
    RUNSYNC(20) RUNSYNC(21) RUNSYNC(22) RUNSYNC(23) RUNSYNC(24)
    RUNSYNC(25) RUNSYNC(26) RUNSYNC(27) RUNSYNC(28)
#undef RUNSYNC
    depth_body<29>(b, y, lane, feats, wpk, cpk, bias, convW, convB, soutw, soutb, out);
}

// ---------------------------------------------------------------------------
extern "C" void kernel_launch(void* const* d_in, const int* in_sizes, int n_in,
                              void* d_out, int out_size, void* d_ws, size_t ws_size,
                              hipStream_t stream) {
    const float* x     = (const float*)d_in[0];
    const float* Wmsd  = (const float*)d_in[1];
    const float* bias  = (const float*)d_in[2];
    const float* convW = (const float*)d_in[3];
    const float* convB = (const float*)d_in[4];
    const float* sinw  = (const float*)d_in[5];
    const float* sinb  = (const float*)d_in[6];
    const float* soutw = (const float*)d_in[7];
    const float* soutb = (const float*)d_in[8];
    float* out = (float*)d_out;

    u32* feats = (u32*)d_ws;                 // 15 pairs x 4 b x 544x544 u32 = 68 MB
    u32* wpk = feats + WPK_OFF;              // 80 MB offset
    u32* cpk = wpk + MSD_DEPTH * NPAIR * 9;  // wpk+4050
    u32* bar = wpk + 8192;                   // own cacheline, past wpk/cpk

    init_bar<<<1, 64, 0, stream>>>(bar);

    void* args[] = {&x, &Wmsd, &bias, &convW, &convB, &sinw, &sinb,
                    &soutw, &soutb, &feats, &wpk, &cpk, &bar, &out};
    hipError_t rc = hipLaunchCooperativeKernel(msd_fused, dim3(NBLK), dim3(TPB),
                                               args, 0u, stream);
    if (rc != hipSuccess) {
        (void)hipGetLastError(); // clear sticky error, take legacy path
        pack_weights<<<16, 256, 0, stream>>>(Wmsd, convW, wpk, cpk);
        zero_halo_kernel<<<(ZSTRIPS + 255) / 256, 256, 0, stream>>>(feats);
        scale_in_kernel<<<NPIX / 8 / 256, 256, 0, stream>>>(x, feats, sinw, sinb);
#define LNCH(I) depth_kernel<I><<<1024, 128, 0, stream>>>(feats, wpk, cpk, bias, convW, convB, soutw, soutb, out);
        LNCH(0)  LNCH(1)  LNCH(2)  LNCH(3)  LNCH(4)
        LNCH(5)  LNCH(6)  LNCH(7)  LNCH(8)  LNCH(9)
        LNCH(10) LNCH(11) LNCH(12) LNCH(13) LNCH(14)
        LNCH(15) LNCH(16) LNCH(17) LNCH(18) LNCH(19)
        LNCH(20) LNCH(21) LNCH(22) LNCH(23) LNCH(24)
        LNCH(25) LNCH(26) LNCH(27) LNCH(28) LNCH(29)
#undef LNCH
    }
}

// Round 2
// 683.139 us; speedup vs baseline: 1.4317x; 1.4317x over previous
//
#include <hip/hip_runtime.h>

// MSDNet on gfx950 — round 14: back to the verified 33-launch structure
// (R13's fused coop kernel regressed 491->907 us: per-block agent release/
// acquire = 512 full L2 writeback/invalidate walks per depth ~= +17 us/depth).
// R13 did show true depth exec ~13 us vs ~2-3 us VALU floor => latency-bound
// at 2 waves/SIMD with a 2-deep pair pipeline (350 cyc compute vs ~600 cyc
// L3 latency). This round: (1) 4-deep pair-pipeline ring, fully unrolled
// (NP<=15 constexpr, all ring indices compile-time -> registers; VGPR is
// free, occupancy is grid-limited); (2) pack/zero-halo/scale-in merged into
// one preamble kernel (disjoint writes). Pair accumulation order unchanged
// => bit-identical to the 491 us baseline.
// Layout: feats = 15 channel-pairs (u32 = 2xf16) x 4 batches x 544x544;
// one wave = one 512-px row (8 px/lane); depth grid 1024x128 (2 waves/blk),
// XCD bands; fdot2 contracts 2 ch/px/tap; depth 29 fuses 1x1 conv + affine.

#define MSD_DEPTH 30
#define NB 4
#define IH 512
#define IW 512
#define HALO 16
#define WPp (IW + 2 * HALO)               /* 544 u32 per row */
#define HPp (IH + 2 * HALO)               /* 544 rows */
#define PLANE_U ((size_t)WPp * HPp)       /* u32 per subplane */
#define PSTR ((size_t)NB * PLANE_U)       /* pair stride (u32) */
#define NPAIR 15
#define NPIX (NB * IH * IW)
#define WPK_OFF ((size_t)20 << 20)        /* u32 offset: 80 MB into ws */
#define ZSTRIPS (32 * (WPp / 4) * NPAIR * NB) /* 261120 */

typedef _Float16 h2v __attribute__((ext_vector_type(2)));
typedef unsigned int u32;

__device__ __forceinline__ float fdot2u(u32 a, u32 b, float c) {
#if __has_builtin(__builtin_amdgcn_fdot2)
    return __builtin_amdgcn_fdot2(__builtin_bit_cast(h2v, a),
                                  __builtin_bit_cast(h2v, b), c, false);
#else
    h2v x = __builtin_bit_cast(h2v, a), y = __builtin_bit_cast(h2v, b);
    return c + (float)x[0] * (float)y[0] + (float)x[1] * (float)y[1];
#endif
}

// ---------------------------------------------------------------------------
// Preamble: pack weights + zero halos + scale input, one kernel (disjoint
// writes: wpk/cpk, halo rows 0..15 & 528..543, interior rows 16..527).
// ---------------------------------------------------------------------------
__global__ __launch_bounds__(256) void preamble_kernel(const float* __restrict__ x,
                                                       const float* __restrict__ Wmsd,
                                                       const float* __restrict__ convW,
                                                       u32* __restrict__ feats,
                                                       u32* __restrict__ wpk,
                                                       u32* __restrict__ cpk,
                                                       const float* __restrict__ sw,
                                                       const float* __restrict__ sb) {
    int idx = blockIdx.x * 256 + threadIdx.x;

    // ---- weight packing: f16 channel-pairs ----
    if (idx < MSD_DEPTH * NPAIR * 9) {
        int I = idx / (NPAIR * 9);
        int rem = idx - I * (NPAIR * 9);
        int p = rem / 9, t = rem - p * 9;
        int NC = I + 1, c0 = 2 * p, c1 = 2 * p + 1;
        h2v pk;
        pk[0] = (_Float16)((c0 < NC) ? Wmsd[((size_t)I * MSD_DEPTH + c0) * 9 + t] : 0.f);
        pk[1] = (_Float16)((c1 < NC) ? Wmsd[((size_t)I * MSD_DEPTH + c1) * 9 + t] : 0.f);
        wpk[idx] = __builtin_bit_cast(u32, pk);
    }
    if (idx < NPAIR) {
        h2v pk;
        pk[0] = (_Float16)convW[2 * idx];
        pk[1] = (_Float16)convW[2 * idx + 1];
        cpk[idx] = __builtin_bit_cast(u32, pk);
    }

    // ---- zero top/bottom 16 full rows of all 60 subplanes ----
    if (idx < ZSTRIPS) {
        const int per = 32 * (WPp / 4); // 32 rows x 136 uint4 strips = 4352
        int sub = idx / per;
        int s = idx - sub * per;
        int rr = s / 136;
        int c4 = (s - rr * 136) * 4;
        int r = (rr < 16) ? rr : (IH + HALO) + (rr - 16);
        uint4 z = {0, 0, 0, 0};
        *(uint4*)(feats + (size_t)sub * PLANE_U + (size_t)r * WPp + c4) = z;
    }

    // ---- input affine -> pair 0 lo16 (hi16 = 0, h0 merged by depth 0) ----
    if (idx < NPIX / 8) {
        int pix = idx * 8;
        int b = pix >> 18;
        int y = (pix >> 9) & 511;
        int xx = pix & 511;
        const float sws = sw[0], sbs = sb[0];
        u32 v[8];
#pragma unroll
        for (int j = 0; j < 8; ++j) {
            _Float16 h = (_Float16)(x[pix + j] * sws + sbs);
            v[j] = (u32)__builtin_bit_cast(unsigned short, h);
        }
        u32* q = feats + (size_t)b * PLANE_U + (size_t)(y + HALO) * WPp + HALO + xx;
        *(uint4*)q = *(uint4*)&v[0];
        *(uint4*)(q + 4) = *(uint4*)&v[4];
    }
}

// ---------------------------------------------------------------------------
// Depth kernel — R12 body with a 4-deep, fully-unrolled pair pipeline.
// ---------------------------------------------------------------------------
template <int I>
__global__ __launch_bounds__(128, 2) void depth_kernel(u32* __restrict__ feats,
                                                       const u32* __restrict__ wpk,
                                                       const u32* __restrict__ cpk,
                                                       const float* __restrict__ bias,
                                                       const float* __restrict__ convW,
                                                       const float* __restrict__ convB,
                                                       const float* __restrict__ soutw,
                                                       const float* __restrict__ soutb,
                                                       float* __restrict__ out) {
    constexpr int D = (I % 10) + 1;
    constexpr int NC = I + 1;
    constexpr int NP = (NC + 1) / 2;
    constexpr bool LAST = (I == MSD_DEPTH - 1);

    const int tid = threadIdx.x;
    const int widx = tid >> 6, lane = tid & 63;
    const int bid = blockIdx.x; // 1024 blocks x 2 waves = 2048 waves = rows
    // XCD band swizzle (validated R4-R8): 2 XCDs per image, contiguous bands.
    const int xcd = bid & 7;
    const int kk = bid >> 3; // 0..127
    const int b = xcd >> 1;
    const int y = (xcd & 1) * 256 + kk * 2 + widx;

    // bpermute byte addresses for lane offsets -2,-1,+1,+2 (wrap is masked).
    const int bp_m2 = ((lane - 2) & 63) << 2;
    const int bp_m1 = ((lane - 1) & 63) << 2;
    const int bp_p1 = ((lane + 1) & 63) << 2;
    const int bp_p2 = ((lane + 2) & 63) << 2;

    u32* const pb = feats + (size_t)b * PLANE_U + (size_t)(y + HALO) * WPp + HALO + lane * 8;

    float acc[8], ydot[8];
#pragma unroll
    for (int j = 0; j < 8; ++j) { acc[j] = 0.f; ydot[j] = 0.f; }

    const u32* const wrb = wpk + (size_t)I * (NPAIR * 9);

    // 4-deep ring of pair buffers; all indices compile-time (full unroll).
    u32 buf[4][3][8];

    auto load_pair = [&](u32 (*bp)[8], int p) {
        const u32* pp = pb + (size_t)p * PSTR;
#pragma unroll
        for (int r = 0; r < 3; ++r) {
            const u32* rp = pp + (ptrdiff_t)(r - 1) * (D * WPp);
            *(uint4*)&bp[r][0] = *(const uint4*)rp;
            *(uint4*)&bp[r][4] = *(const uint4*)(rp + 4);
        }
    };

    // w[k] = dword at row-pixel (lane*8 + k + shift), 0 outside [0,512).
    auto window = [&](const u32* d, int shift, u32* w) {
#pragma unroll
        for (int k = 0; k < 8; ++k) {
            int off = k + shift; // constant-folded (shift = +-D, k unrolled)
            if (off >= 0 && off < 8) {
                w[k] = d[off];
            } else {
                int q = off >> 3;            // floor div 8: -2,-1,1,2
                int idx = off - q * 8;       // 0..7
                int addr = (q == -2) ? bp_m2
                         : (q == -1) ? bp_m1
                         : (q == 1)  ? bp_p1 : bp_p2;
                u32 t = (u32)__builtin_amdgcn_ds_bpermute(addr, (int)d[idx]);
                bool valid = (q < 0) ? (lane >= -q) : (lane <= 63 - q);
                w[k] = valid ? t : 0u;
            }
        }
    };

    auto compute = [&](u32 (*bp)[8], int p) {
        const u32* wq = wrb + p * 9; // wave-uniform -> s_load
        const u32 cw = LAST ? cpk[p] : 0u;
#pragma unroll
        for (int r = 0; r < 3; ++r) {
            u32* d = bp[r];
            u32 wl[8], wrr[8];
            window(d, -D, wl);
            window(d, D, wrr);
            const u32 w0 = wq[r * 3 + 0], w1 = wq[r * 3 + 1], w2 = wq[r * 3 + 2];
#pragma unroll
            for (int k = 0; k < 8; ++k) {
                float a = acc[k];
                a = fdot2u(wl[k], w0, a);
                a = fdot2u(d[k], w1, a);
                a = fdot2u(wrr[k], w2, a);
                acc[k] = a;
            }
            if (LAST && r == 1) {
#pragma unroll
                for (int k = 0; k < 8; ++k) ydot[k] = fdot2u(d[k], cw, ydot[k]);
            }
        }
    };

    // Prologue: fill up to 3 ring slots.
#pragma unroll
    for (int q = 0; q < 3; ++q)
        if (q < NP) load_pair(buf[q], q);

    // Main: fully unrolled; 3 pair-loads in flight under every compute.
#pragma unroll
    for (int p = 0; p < NP; ++p) {
        if (p + 3 < NP) load_pair(buf[(p + 3) & 3], p + 3);
        compute(buf[p & 3], p);
    }

    const float b0 = bias[I];
    if (!LAST) {
        // Merge h (channel NC) into pair NC>>1. NC odd: hi16 (partner lo16 =
        // channel NC-1, reloaded L2-hot). NC even: lo16, hi16 = 0.
        u32 part[8];
        if constexpr ((NC & 1) != 0) {
            const u32* rp = pb + (size_t)(NP - 1) * PSTR;
            *(uint4*)&part[0] = *(const uint4*)rp;
            *(uint4*)&part[4] = *(const uint4*)(rp + 4);
        }
        u32 mg[8];
#pragma unroll
        for (int j = 0; j < 8; ++j) {
            float h = acc[j] + b0;
            h = h > 0.f ? h : 0.f;
            u32 h16 = (u32)__builtin_bit_cast(unsigned short, (_Float16)h);
            if constexpr ((NC & 1) != 0)
                mg[j] = (part[j] & 0xFFFFu) | (h16 << 16);
            else
                mg[j] = h16;
        }
        u32* q = feats + (size_t)(NC >> 1) * PSTR + (size_t)b * PLANE_U +
                 (size_t)(y + HALO) * WPp + HALO + lane * 8;
        *(uint4*)q = *(uint4*)&mg[0];
        *(uint4*)(q + 4) = *(uint4*)&mg[4];
    } else {
        const float cw30 = convW[MSD_DEPTH];
        const float cb = convB[0], ow = soutw[0], ob = soutb[0];
        float* q = out + ((size_t)b * IH + y) * IW + lane * 8;
        float o[8];
#pragma unroll
        for (int j = 0; j < 8; ++j) {
            float h = acc[j] + b0;
            h = h > 0.f ? h : 0.f;
            float yv = ydot[j] + cw30 * h + cb;
            o[j] = yv * ow + ob;
        }
        *(uint4*)q = *(uint4*)&o[0];
        *(uint4*)(q + 4) = *(uint4*)&o[4];
    }
}

// ---------------------------------------------------------------------------
extern "C" void kernel_launch(void* const* d_in, const int* in_sizes, int n_in,
                              void* d_out, int out_size, void* d_ws, size_t ws_size,
                              hipStream_t stream) {
    const float* x     = (const float*)d_in[0];
    const float* Wmsd  = (const float*)d_in[1];
    const float* bias  = (const float*)d_in[2];
    const float* convW = (const float*)d_in[3];
    const float* convB = (const float*)d_in[4];
    const float* sinw  = (const float*)d_in[5];
    const float* sinb  = (const float*)d_in[6];
    const float* soutw = (const float*)d_in[7];
    const float* soutb = (const float*)d_in[8];
    float* out = (float*)d_out;

    u32* feats = (u32*)d_ws;                 // 15 pairs x 4 b x 544x544 u32 = 68 MB
    u32* wpk = feats + WPK_OFF;              // 80 MB offset
    u32* cpk = wpk + MSD_DEPTH * NPAIR * 9;

    // ZSTRIPS (261120) dominates the preamble index space: 1020 blocks x 256.
    preamble_kernel<<<(ZSTRIPS + 255) / 256, 256, 0, stream>>>(x, Wmsd, convW,
                                                               feats, wpk, cpk,
                                                               sinw, sinb);

#define LNCH(I) depth_kernel<I><<<1024, 128, 0, stream>>>(feats, wpk, cpk, bias, convW, convB, soutw, soutb, out);
    LNCH(0)  LNCH(1)  LNCH(2)  LNCH(3)  LNCH(4)
    LNCH(5)  LNCH(6)  LNCH(7)  LNCH(8)  LNCH(9)
    LNCH(10) LNCH(11) LNCH(12) LNCH(13) LNCH(14)
    LNCH(15) LNCH(16) LNCH(17) LNCH(18) LNCH(19)
    LNCH(20) LNCH(21) LNCH(22) LNCH(23) LNCH(24)
    LNCH(25) LNCH(26) LNCH(27) LNCH(28) LNCH(29)
#undef LNCH
}

// Round 3
// 390.352 us; speedup vs baseline: 2.5056x; 1.7501x over previous
//
#include <hip/hip_runtime.h>

// MSDNet on gfx950 — round 15. R14 post-mortem: VGPR=84 < ring size 96 =>
// buf[(p+3)&3] (runtime index at SROA time) demoted the whole ring to
// scratch (rule #20) -> 47 us depths. This round:
//  (1) revert to the NAMED A/B 2-deep pipeline (R12-verified, promoted);
//  (2) kill the bpermute window machinery: zero the SIDE halo columns in
//      the preamble, then load each lane's horizontal span [col-D, col+8+D)
//      as 16B-aligned uint4 chunks (chunk range constexpr per D; lane base
//      32B-aligned). Window taps become compile-time register indices:
//      wl[k]=s[12-D+k], d[k]=s[12+k], wr[k]=s[12+D+k]. Zero VALU / zero
//      LDS-pipe per window vs ~40 bpermute+cndmask before. Accumulation
//      order unchanged -> numerics identical to the 491 us baseline.
// Layout: feats = 15 channel-pairs (u32 = 2xf16) x 4 batches x 544x544;
// one wave = one 512-px row (8 px/lane); depth grid 1024x128 (2 waves/blk),
// XCD bands; fdot2 contracts 2 ch/px/tap; depth 29 fuses 1x1 conv + affine.

#define MSD_DEPTH 30
#define NB 4
#define IH 512
#define IW 512
#define HALO 16
#define WPp (IW + 2 * HALO)               /* 544 u32 per row */
#define HPp (IH + 2 * HALO)               /* 544 rows */
#define PLANE_U ((size_t)WPp * HPp)       /* u32 per subplane */
#define PSTR ((size_t)NB * PLANE_U)       /* pair stride (u32) */
#define NPAIR 15
#define NPIX (NB * IH * IW)
#define WPK_OFF ((size_t)20 << 20)        /* u32 offset: 80 MB into ws */
#define ZSTRIPS (32 * (WPp / 4) * NPAIR * NB)   /* top/bot: 261120 uint4 */
#define SSTRIPS (512 * 8 * NPAIR * NB)          /* sides:   245760 uint4 */
#define TOTZ (ZSTRIPS + SSTRIPS)

typedef _Float16 h2v __attribute__((ext_vector_type(2)));
typedef unsigned int u32;

__device__ __forceinline__ float fdot2u(u32 a, u32 b, float c) {
#if __has_builtin(__builtin_amdgcn_fdot2)
    return __builtin_amdgcn_fdot2(__builtin_bit_cast(h2v, a),
                                  __builtin_bit_cast(h2v, b), c, false);
#else
    h2v x = __builtin_bit_cast(h2v, a), y = __builtin_bit_cast(h2v, b);
    return c + (float)x[0] * (float)y[0] + (float)x[1] * (float)y[1];
#endif
}

// ---------------------------------------------------------------------------
// Preamble: pack weights + zero halos (top/bottom rows AND side columns) +
// scale input. All writes disjoint.
// ---------------------------------------------------------------------------
__global__ __launch_bounds__(256) void preamble_kernel(const float* __restrict__ x,
                                                       const float* __restrict__ Wmsd,
                                                       const float* __restrict__ convW,
                                                       u32* __restrict__ feats,
                                                       u32* __restrict__ wpk,
                                                       u32* __restrict__ cpk,
                                                       const float* __restrict__ sw,
                                                       const float* __restrict__ sb) {
    int idx = blockIdx.x * 256 + threadIdx.x;

    // ---- weight packing: f16 channel-pairs ----
    if (idx < MSD_DEPTH * NPAIR * 9) {
        int I = idx / (NPAIR * 9);
        int rem = idx - I * (NPAIR * 9);
        int p = rem / 9, t = rem - p * 9;
        int NC = I + 1, c0 = 2 * p, c1 = 2 * p + 1;
        h2v pk;
        pk[0] = (_Float16)((c0 < NC) ? Wmsd[((size_t)I * MSD_DEPTH + c0) * 9 + t] : 0.f);
        pk[1] = (_Float16)((c1 < NC) ? Wmsd[((size_t)I * MSD_DEPTH + c1) * 9 + t] : 0.f);
        wpk[idx] = __builtin_bit_cast(u32, pk);
    }
    if (idx < NPAIR) {
        h2v pk;
        pk[0] = (_Float16)convW[2 * idx];
        pk[1] = (_Float16)convW[2 * idx + 1];
        cpk[idx] = __builtin_bit_cast(u32, pk);
    }

    // ---- zero top/bottom 16 full rows of all 60 subplanes ----
    if (idx < ZSTRIPS) {
        const int per = 32 * (WPp / 4); // 32 rows x 136 uint4 strips = 4352
        int sub = idx / per;
        int s = idx - sub * per;
        int rr = s / 136;
        int c4 = (s - rr * 136) * 4;
        int r = (rr < 16) ? rr : (IH + HALO) + (rr - 16);
        uint4 z = {0, 0, 0, 0};
        *(uint4*)(feats + (size_t)sub * PLANE_U + (size_t)r * WPp + c4) = z;
    } else if (idx < TOTZ) {
        // ---- zero side halo cols [0,16) and [528,544) of interior rows ----
        int s = idx - ZSTRIPS;
        int sub = s >> 12;            // / 4096 (= 512 rows * 8 strips)
        int rem = s & 4095;
        int r = HALO + (rem >> 3);    // 16..527
        int e = rem & 7;
        int c4 = (e < 4) ? (e * 4) : (IW + HALO + (e - 4) * 4);
        uint4 z = {0, 0, 0, 0};
        *(uint4*)(feats + (size_t)sub * PLANE_U + (size_t)r * WPp + c4) = z;
    }

    // ---- input affine -> pair 0 lo16 (hi16 = 0, h0 merged by depth 0) ----
    if (idx < NPIX / 8) {
        int pix = idx * 8;
        int b = pix >> 18;
        int y = (pix >> 9) & 511;
        int xx = pix & 511;
        const float sws = sw[0], sbs = sb[0];
        u32 v[8];
#pragma unroll
        for (int j = 0; j < 8; ++j) {
            _Float16 h = (_Float16)(x[pix + j] * sws + sbs);
            v[j] = (u32)__builtin_bit_cast(unsigned short, h);
        }
        u32* q = feats + (size_t)b * PLANE_U + (size_t)(y + HALO) * WPp + HALO + xx;
        *(uint4*)q = *(uint4*)&v[0];
        *(uint4*)(q + 4) = *(uint4*)&v[4];
    }
}

// ---------------------------------------------------------------------------
// Depth kernel: named 2-deep pair pipeline + constexpr aligned-span windows.
// ---------------------------------------------------------------------------
template <int I>
__global__ __launch_bounds__(128, 2) void depth_kernel(u32* __restrict__ feats,
                                                       const u32* __restrict__ wpk,
                                                       const u32* __restrict__ cpk,
                                                       const float* __restrict__ bias,
                                                       const float* __restrict__ convW,
                                                       const float* __restrict__ convB,
                                                       const float* __restrict__ soutw,
                                                       const float* __restrict__ soutb,
                                                       float* __restrict__ out) {
    constexpr int D = (I % 10) + 1;
    constexpr int NC = I + 1;
    constexpr int NP = (NC + 1) / 2;
    constexpr bool LAST = (I == MSD_DEPTH - 1);
    // Horizontal span per lane: dwords [base-12, base+20) relative to its 8-px
    // window; taps live at s[12-D+k], s[12+k], s[12+D+k]. Needed 16B chunks:
    constexpr int C0 = (12 - D) >> 2;   // D<=4 -> 2, D<=8 -> 1, else 0
    constexpr int C1 = (19 + D) >> 2;   // D<=4 -> 5, D<=8 -> 6, else 7

    const int tid = threadIdx.x;
    const int widx = tid >> 6, lane = tid & 63;
    const int bid = blockIdx.x; // 1024 blocks x 2 waves = 2048 waves = rows
    // XCD band swizzle (validated R4-R8): 2 XCDs per image, contiguous bands.
    const int xcd = bid & 7;
    const int kk = bid >> 3; // 0..127
    const int b = xcd >> 1;
    const int y = (xcd & 1) * 256 + kk * 2 + widx;

    // pb: dword col HALO + lane*8 -> byte 64 + 32*lane (32B-aligned).
    u32* const pb = feats + (size_t)b * PLANE_U + (size_t)(y + HALO) * WPp + HALO + lane * 8;

    float acc[8], ydot[8];
#pragma unroll
    for (int j = 0; j < 8; ++j) { acc[j] = 0.f; ydot[j] = 0.f; }

    const u32* const wrb = wpk + (size_t)I * (NPAIR * 9);

    // Named double buffers (SROA-promoted; R14's indexed ring went to scratch).
    u32 A[3][32], B[3][32];

    auto load_pair = [&](u32 (*bp)[32], int p) {
        const u32* pp = pb + (size_t)p * PSTR;
#pragma unroll
        for (int r = 0; r < 3; ++r) {
            const u32* rp = pp + (ptrdiff_t)(r - 1) * (D * WPp);
#pragma unroll
            for (int c = C0; c <= C1; ++c)
                *(uint4*)&bp[r][4 * c] = *(const uint4*)(rp - 12 + 4 * c);
        }
    };

    auto compute = [&](u32 (*bp)[32], int p) {
        const u32* wq = wrb + p * 9; // wave-uniform -> s_load
        const u32 cw = LAST ? cpk[p] : 0u;
#pragma unroll
        for (int r = 0; r < 3; ++r) {
            const u32* s = bp[r];
            const u32 w0 = wq[r * 3 + 0], w1 = wq[r * 3 + 1], w2 = wq[r * 3 + 2];
#pragma unroll
            for (int k = 0; k < 8; ++k) {
                float a = acc[k];
                a = fdot2u(s[12 - D + k], w0, a);   // left tap  (const idx)
                a = fdot2u(s[12 + k],     w1, a);   // center
                a = fdot2u(s[12 + D + k], w2, a);   // right
                acc[k] = a;
            }
            if (LAST && r == 1) {
#pragma unroll
                for (int k = 0; k < 8; ++k) ydot[k] = fdot2u(s[12 + k], cw, ydot[k]);
            }
        }
    };

    // 2-deep software pipeline over channel pairs (R12-verified structure).
    load_pair(A, 0);
    int p = 0;
    for (; p + 2 <= NP; p += 2) {
        load_pair(B, p + 1);
        compute(A, p);
        if (p + 2 < NP) load_pair(A, p + 2);
        compute(B, p + 1);
    }
    if (p < NP) compute(A, p);

    const float b0 = bias[I];
    if (!LAST) {
        // Merge h (channel NC) into pair NC>>1. NC odd: hi16 (partner lo16 =
        // channel NC-1, reloaded L2-hot). NC even: lo16, hi16 = 0.
        u32 part[8];
        if constexpr ((NC & 1) != 0) {
            const u32* rp = pb + (size_t)(NP - 1) * PSTR;
            *(uint4*)&part[0] = *(const uint4*)rp;
            *(uint4*)&part[4] = *(const uint4*)(rp + 4);
        }
        u32 mg[8];
#pragma unroll
        for (int j = 0; j < 8; ++j) {
            float h = acc[j] + b0;
            h = h > 0.f ? h : 0.f;
            u32 h16 = (u32)__builtin_bit_cast(unsigned short, (_Float16)h);
            if constexpr ((NC & 1) != 0)
                mg[j] = (part[j] & 0xFFFFu) | (h16 << 16);
            else
                mg[j] = h16;
        }
        u32* q = feats + (size_t)(NC >> 1) * PSTR + (size_t)b * PLANE_U +
                 (size_t)(y + HALO) * WPp + HALO + lane * 8;
        *(uint4*)q = *(uint4*)&mg[0];
        *(uint4*)(q + 4) = *(uint4*)&mg[4];
    } else {
        const float cw30 = convW[MSD_DEPTH];
        const float cb = convB[0], ow = soutw[0], ob = soutb[0];
        float* q = out + ((size_t)b * IH + y) * IW + lane * 8;
        float o[8];
#pragma unroll
        for (int j = 0; j < 8; ++j) {
            float h = acc[j] + b0;
            h = h > 0.f ? h : 0.f;
            float yv = ydot[j] + cw30 * h + cb;
            o[j] = yv * ow + ob;
        }
        *(uint4*)q = *(uint4*)&o[0];
        *(uint4*)(q + 4) = *(uint4*)&o[4];
    }
}

// ---------------------------------------------------------------------------
extern "C" void kernel_launch(void* const* d_in, const int* in_sizes, int n_in,
                              void* d_out, int out_size, void* d_ws, size_t ws_size,
                              hipStream_t stream) {
    const float* x     = (const float*)d_in[0];
    const float* Wmsd  = (const float*)d_in[1];
    const float* bias  = (const float*)d_in[2];
    const float* convW = (const float*)d_in[3];
    const float* convB = (const float*)d_in[4];
    const float* sinw  = (const float*)d_in[5];
    const float* sinb  = (const float*)d_in[6];
    const float* soutw = (const float*)d_in[7];
    const float* soutb = (const float*)d_in[8];
    float* out = (float*)d_out;

    u32* feats = (u32*)d_ws;                 // 15 pairs x 4 b x 544x544 u32 = 68 MB
    u32* wpk = feats + WPK_OFF;              // 80 MB offset
    u32* cpk = wpk + MSD_DEPTH * NPAIR * 9;

    preamble_kernel<<<(TOTZ + 255) / 256, 256, 0, stream>>>(x, Wmsd, convW,
                                                            feats, wpk, cpk,
                                                            sinw, sinb);

#define LNCH(I) depth_kernel<I><<<1024, 128, 0, stream>>>(feats, wpk, cpk, bias, convW, convB, soutw, soutb, out);
    LNCH(0)  LNCH(1)  LNCH(2)  LNCH(3)  LNCH(4)
    LNCH(5)  LNCH(6)  LNCH(7)  LNCH(8)  LNCH(9)
    LNCH(10) LNCH(11) LNCH(12) LNCH(13) LNCH(14)
    LNCH(15) LNCH(16) LNCH(17) LNCH(18) LNCH(19)
    LNCH(20) LNCH(21) LNCH(22) LNCH(23) LNCH(24)
    LNCH(25) LNCH(26) LNCH(27) LNCH(28) LNCH(29)
#undef LNCH
}